// Round 7
// baseline (146.992 us; speedup 1.0000x reference)
//
#include <hip/hip_runtime.h>

// DiceLoss: B=2, C=14, D=48, H=256, W=256, organs 1..13, weights all 1.0.
// Per batch b: S = sum of pred at target channel (t in 1..13),
//              Q = sum over c=1..13 of pred[c]^2, cnt = #{t>=1}.
// dice_stage = 2S/(Q + cnt + 13*EPS); out = mean_b(2 - dice1 - dice2).
//
// R7: R6's LDS ring (global_load_lds w16, counted vmcnt(2), no barriers,
// 2048 blocks = 8/CU = 32 waves/CU) plus:
//  - NT cache policy (aux=2) on streaming loads: data is touched exactly
//    once, so skip L2 retention (fill kernels stream at 6.8 TB/s; we were
//    at ~5.2 with normal allocate-on-read).
//  - static issue addressing: channel body unrolled with compile-time ring
//    slots (channel pairs -> slotbase 0/2), bases advanced by +NV4. No
//    division/branch in the hot loop.
//  - prologue tiles issued BEFORE the target-window read (overlap).

namespace {
constexpr int BATCH = 2;
constexpr int CH = 14;
constexpr int ORGANS = 13;
constexpr unsigned NV4 = 786432u;        // vec4 groups per (b, channel) slice
constexpr int TPB = 256;
constexpr int NBLK = 2048;               // 1024 per batch, 8/CU exactly
constexpr unsigned WIN = 768u;           // groups per block window (1024*768 = NV4)
constexpr int KT = 3;                    // tiles per (c, stage): WIN/256
constexpr int NBUF = 4;                  // ring slots (4 KB each) -> 16 KB
constexpr double EPS = 1e-05;
}

// global -> LDS async, 16B/lane, NT cache policy (cpol bit1 = nt on gfx950).
#define LOADLDS(srcptr, slot)                                              \
    __builtin_amdgcn_global_load_lds(                                      \
        (const __attribute__((address_space(1))) unsigned*)(srcptr),       \
        (__attribute__((address_space(3))) unsigned*)&ring[(slot)][ldsq],  \
        16, 0, 2)

__global__ __launch_bounds__(TPB, 8) void dice_lds(
    const float* __restrict__ p1g, const float* __restrict__ p2g,
    const int* __restrict__ tg, double* __restrict__ part)
{
    __shared__ float4 ring[NBUF][TPB];   // 16 KB ring
    __shared__ float red[4][5];

    const unsigned blk = blockIdx.x;
    const unsigned b = blk >> 10;                // batch
    const unsigned w0 = (blk & 1023u) * WIN;     // window start (groups)
    const unsigned tid = threadIdx.x;
    const unsigned wid = tid >> 6;
    const unsigned ldsq = wid * 64u;             // this wave's ring quarter

    // Channel walkers (float4 index space), start at channel 1 of each stage.
    const float4* a0 = reinterpret_cast<const float4*>(p1g)
        + (unsigned long long)(b * CH + 1) * NV4 + w0 + tid;
    const float4* a1 = reinterpret_cast<const float4*>(p2g)
        + (unsigned long long)(b * CH + 1) * NV4 + w0 + tid;

    // Prologue: tiles 0..2 (stage1, channel 1) in flight before target read.
    LOADLDS(a0 + 0 * TPB, 0);
    LOADLDS(a0 + 1 * TPB, 1);
    LOADLDS(a0 + 2 * TPB, 2);

    // Target window once: KT int4 per thread; pack labels into bytes.
    unsigned tw[KT];
    float cn = 0.f;
    {
        const int4* __restrict__ pT =
            reinterpret_cast<const int4*>(tg) + b * NV4 + w0;
        #pragma unroll
        for (int k = 0; k < KT; ++k) {
            const int4 t = pT[k * TPB + tid];
            cn += (float)((t.x > 0) + (t.y > 0) + (t.z > 0) + (t.w > 0));
            tw[k] = (unsigned)t.x | ((unsigned)t.y << 8)
                  | ((unsigned)t.z << 16) | ((unsigned)t.w << 24);
        }
    }

    float s1 = 0.f, q1 = 0.f, s2 = 0.f, q2 = 0.f;
    unsigned cc = 1;                             // current organ id

    auto acc4 = [&](const float4 A, int k, float& q, float& s) {
        const unsigned t4 = tw[k];
        q = fmaf(A.x, A.x, q); q = fmaf(A.y, A.y, q);
        q = fmaf(A.z, A.z, q); q = fmaf(A.w, A.w, q);
        const bool ex = ((t4 & 255u) == cc);
        const bool ey = (((t4 >> 8) & 255u) == cc);
        const bool ez = (((t4 >> 16) & 255u) == cc);
        const bool ew = ((t4 >> 24) == cc);
        s += (ex ? A.x : 0.f) + (ey ? A.y : 0.f)
           + (ez ? A.z : 0.f) + (ew ? A.w : 0.f);
    };

    // One channel: consume 6 tiles (3 stage1 -> q1/s1, 3 stage2 -> q2/s2),
    // issue the next 6 (this channel's stage2, next channel's stage1).
    // SB = (6*c) & 3, compile-time 0 or 2 via pair-unrolling.
    auto chan = [&](int SB) {
        #pragma unroll
        for (int p = 0; p < 3; ++p) {
            asm volatile("s_waitcnt vmcnt(2)" ::: "memory");
            LOADLDS(a1 + p * TPB, (SB + p + 3) & 3);
            acc4(ring[(SB + p) & 3][tid], p, q1, s1);
        }
        #pragma unroll
        for (int p = 0; p < 3; ++p) {
            asm volatile("s_waitcnt vmcnt(2)" ::: "memory");
            LOADLDS(a0 + NV4 + p * TPB, (SB + p + 2) & 3);
            acc4(ring[(SB + p + 3) & 3][tid], p, q2, s2);
        }
        a0 += NV4; a1 += NV4; ++cc;
    };

    for (int cp = 0; cp < 6; ++cp) { chan(0); chan(2); }   // channels 1..12

    // Peel last channel (cc==13 here, tiles 72..77, slotbase 0): drain tail.
    #pragma unroll
    for (int p = 0; p < 3; ++p) {
        asm volatile("s_waitcnt vmcnt(2)" ::: "memory");
        LOADLDS(a1 + p * TPB, (p + 3) & 3);
        acc4(ring[p][tid], p, q1, s1);
    }
    asm volatile("s_waitcnt vmcnt(2)" ::: "memory");
    acc4(ring[3][tid], 0, q2, s2);
    asm volatile("s_waitcnt vmcnt(1)" ::: "memory");
    acc4(ring[0][tid], 1, q2, s2);
    asm volatile("s_waitcnt vmcnt(0)" ::: "memory");
    acc4(ring[1][tid], 2, q2, s2);

    // ---- Block reduction: wave shuffle then LDS across 4 waves ----
    float vals[5] = {s1, q1, s2, q2, cn};
    #pragma unroll
    for (int k = 0; k < 5; ++k) {
        float v = vals[k];
        #pragma unroll
        for (int off = 32; off > 0; off >>= 1) v += __shfl_down(v, off, 64);
        vals[k] = v;
    }
    const int lane = tid & 63;
    if (lane == 0) {
        #pragma unroll
        for (int k = 0; k < 5; ++k) red[wid][k] = vals[k];
    }
    __syncthreads();
    if (tid == 0) {
        #pragma unroll
        for (int k = 0; k < 5; ++k)
            part[blk * 5 + k] =
                (double)(red[0][k] + red[1][k] + red[2][k] + red[3][k]);
    }
}

__global__ __launch_bounds__(256) void dice_final(
    const double* __restrict__ part, float* __restrict__ out)
{
    __shared__ double redd[BATCH][4][5];
    const int tid = threadIdx.x, lane = tid & 63, wv = tid >> 6;
    #pragma unroll
    for (int b = 0; b < BATCH; ++b) {
        double loc[5] = {0, 0, 0, 0, 0};
        for (int i = tid; i < NBLK / BATCH; i += 256) {
            const double* p = part + ((unsigned)(b * (NBLK / BATCH) + i)) * 5u;
            #pragma unroll
            for (int k = 0; k < 5; ++k) loc[k] += p[k];
        }
        #pragma unroll
        for (int k = 0; k < 5; ++k) {
            double v = loc[k];
            #pragma unroll
            for (int off = 32; off > 0; off >>= 1) v += __shfl_down(v, off, 64);
            loc[k] = v;
        }
        if (lane == 0) {
            #pragma unroll
            for (int k = 0; k < 5; ++k) redd[b][wv][k] = loc[k];
        }
    }
    __syncthreads();
    if (tid == 0) {
        double total = 0.0;
        #pragma unroll
        for (int b = 0; b < BATCH; ++b) {
            double a[5];
            #pragma unroll
            for (int k = 0; k < 5; ++k)
                a[k] = redd[b][0][k] + redd[b][1][k] + redd[b][2][k] + redd[b][3][k];
            const double den1 = a[1] + a[4] + (double)ORGANS * EPS;
            const double den2 = a[3] + a[4] + (double)ORGANS * EPS;
            total += 2.0 - (2.0 * a[0] / den1 + 2.0 * a[2] / den2);
        }
        *out = (float)(total / BATCH);
    }
}

extern "C" void kernel_launch(void* const* d_in, const int* in_sizes, int n_in,
                              void* d_out, int out_size, void* d_ws, size_t ws_size,
                              hipStream_t stream)
{
    const float* p1 = (const float*)d_in[0];
    const float* p2 = (const float*)d_in[1];
    const int* tg = (const int*)d_in[2];
    float* out = (float*)d_out;
    double* part = (double*)d_ws;    // 2048*5 doubles = 80 KB; all written per call

    dice_lds<<<dim3(NBLK), dim3(TPB), 0, stream>>>(p1, p2, tg, part);
    dice_final<<<1, 256, 0, stream>>>(part, out);
}